// Round 8
// baseline (109.115 us; speedup 1.0000x reference)
//
#include <hip/hip_runtime.h>
#include <hip/hip_bf16.h>

// Problem constants: B=64, N=32, S=256, D=128
#define B_SZ 64

typedef __attribute__((ext_vector_type(8))) short bf16x8;
typedef __attribute__((ext_vector_type(4))) float f32x4;

static __device__ __forceinline__ unsigned short f2bf(float f) {
    __hip_bfloat16 h = __float2bfloat16(f);
    return *reinterpret_cast<unsigned short*>(&h);
}

// Load 8 consecutive fp32 (32 B), convert to one bf16x8 fragment in-register.
static __device__ __forceinline__ bf16x8 cvt_frag(const float* __restrict__ src) {
    float4 a = reinterpret_cast<const float4*>(src)[0];
    float4 b = reinterpret_cast<const float4*>(src)[1];
    union { bf16x8 v; unsigned short u[8]; } t;
    t.u[0] = f2bf(a.x); t.u[1] = f2bf(a.y); t.u[2] = f2bf(a.z); t.u[3] = f2bf(a.w);
    t.u[4] = f2bf(b.x); t.u[5] = f2bf(b.y); t.u[6] = f2bf(b.z); t.u[7] = f2bf(b.w);
    return t.v;
}

#define MFMA(A, Bv, C) __builtin_amdgcn_mfma_f32_16x16x32_bf16(A, Bv, C, 0, 0, 0)

// One-kernel MaxSim, fp32 inputs, in-register bf16 conversion.
// idx < 512: c = idx>>3, wave w handles queries b = (idx&7)*8 + 2w + {0,1}, all 256 s.
// idx >= 512: b = idx-512 vs neg doc b (waves duplicate; wave 0 writes).
// Doc staged to 64 KiB LDS in B-fragment order with XOR swizzle:
//   element (s, kc=k/8) at logical idx16 L = ch*1024 + (kc>>2)*256 + nt*64 + (kc&3)*16 + (s&15)
//   physical = L ^ ((kc>>2)<<1)   [reads conflict-free; staging writes 4-way]
__global__ __launch_bounds__(256, 2) void maxsim_kernel(const float* __restrict__ q,
                                                        const float* __restrict__ dd,
                                                        const float* __restrict__ nd,
                                                        float* __restrict__ scores) {
    const int idx = blockIdx.x, tid = threadIdx.x;
    const int wave = tid >> 6, lane = tid & 63;
    const int l15 = lane & 15, l4 = lane >> 4;

    __shared__ bf16x8 docB[4096];        // 64 KiB

    int b0, b1, ccol;
    const float* docf;
    if (idx < 512) {
        const int c = idx >> 3, g = idx & 7;
        b0 = g * 8 + wave * 2; b1 = b0 + 1; ccol = c;
        docf = dd + (size_t)c * 32768;
    } else {
        b0 = b1 = idx - 512; ccol = B_SZ;
        docf = nd + (size_t)b0 * 32768;
    }

    // ---- A fragments for this wave's 2 queries: fp32 direct, cvt in-register ----
    // A[m = l15][k = l4*8 + j] for tile (kk, mt): 8 consecutive floats.
    bf16x8 Af[2][4][2];
    #pragma unroll
    for (int kk = 0; kk < 4; ++kk)
        #pragma unroll
        for (int mt = 0; mt < 2; ++mt) {
            const int off = (mt * 16 + l15) * 128 + kk * 32 + l4 * 8;
            Af[0][kk][mt] = cvt_frag(q + (size_t)b0 * 4096 + off);
            Af[1][kk][mt] = cvt_frag(q + (size_t)b1 * 4096 + off);
        }

    // ---- stage this wave's doc chunk (64 s-rows x 128 k, fp32 -> bf16 -> LDS) ----
    {
        const float* dsrc = docf + wave * 8192;      // chunk = 64 rows * 128
        #pragma unroll
        for (int f = 0; f < 16; ++f) {
            const int s_local = f * 4 + l4;          // 0..63
            const int kc = l15;                      // 0..15
            bf16x8 v = cvt_frag(dsrc + s_local * 128 + kc * 8);
            const int logical = wave * 1024 + (kc >> 2) * 256 + (s_local >> 4) * 64
                                + (kc & 3) * 16 + (s_local & 15);
            docB[logical ^ ((kc >> 2) << 1)] = v;
        }
    }
    __syncthreads();

    // ---- compute: per-lane running row-max across the 4 s-chunks ----
    float rmax[2][2][4];
    #pragma unroll
    for (int qi = 0; qi < 2; ++qi)
        #pragma unroll
        for (int mt = 0; mt < 2; ++mt)
            #pragma unroll
            for (int r = 0; r < 4; ++r) rmax[qi][mt][r] = -3.0e38f;

    #pragma unroll
    for (int i = 0; i < 4; ++i) {
        const int ch = (wave + i) & 3;
        f32x4 acc[2][2][4] = {};         // [qi][mt][nt]
        #pragma unroll
        for (int kk = 0; kk < 4; ++kk) {
            const int rbase = ch * 1024 + kk * 256 + (lane ^ (kk << 1));
            #pragma unroll
            for (int nt = 0; nt < 4; ++nt) {
                bf16x8 Bv = docB[rbase + nt * 64];
                acc[0][0][nt] = MFMA(Af[0][kk][0], Bv, acc[0][0][nt]);
                acc[0][1][nt] = MFMA(Af[0][kk][1], Bv, acc[0][1][nt]);
                acc[1][0][nt] = MFMA(Af[1][kk][0], Bv, acc[1][0][nt]);
                acc[1][1][nt] = MFMA(Af[1][kk][1], Bv, acc[1][1][nt]);
            }
        }
        #pragma unroll
        for (int qi = 0; qi < 2; ++qi)
            #pragma unroll
            for (int mt = 0; mt < 2; ++mt)
                #pragma unroll
                for (int r = 0; r < 4; ++r)
                    rmax[qi][mt][r] = fmaxf(rmax[qi][mt][r],
                        fmaxf(fmaxf(acc[qi][mt][0][r], acc[qi][mt][1][r]),
                              fmaxf(acc[qi][mt][2][r], acc[qi][mt][3][r])));
    }

    // ---- epilogue: butterfly max over 16 col-residues, sum the 32 rows ----
    #pragma unroll
    for (int qi = 0; qi < 2; ++qi) {
        float part = 0.0f;
        #pragma unroll
        for (int mt = 0; mt < 2; ++mt)
            #pragma unroll
            for (int r = 0; r < 4; ++r) {
                float m = rmax[qi][mt][r];
                m = fmaxf(m, __shfl_xor(m, 1, 64));
                m = fmaxf(m, __shfl_xor(m, 2, 64));
                m = fmaxf(m, __shfl_xor(m, 4, 64));
                m = fmaxf(m, __shfl_xor(m, 8, 64));
                part += m;               // row n = mt*16 + l4*4 + r
            }
        part += __shfl_xor(part, 16, 64);
        part += __shfl_xor(part, 32, 64);
        const int b = qi ? b1 : b0;
        if (lane == 0 && (idx < 512 ? true : (wave == 0 && qi == 0)))
            scores[(size_t)b * 65 + ccol] = part;
    }
}

static __device__ __forceinline__ float softplusf(float x) {
    return fmaxf(x, 0.0f) + log1pf(expf(-fabsf(x)));
}

__global__ __launch_bounds__(64) void loss_kernel(const float* __restrict__ scores,
                                                  float* __restrict__ out) {
    const int b = threadIdx.x;           // 64 threads = 1 wave
    const float* row = scores + b * 65;
    const float pos  = row[b];
    const float negq = row[64];
    float nib = -1e30f;
    #pragma unroll
    for (int c = 0; c < B_SZ; ++c) {
        float v = row[c] - ((c == b) ? 1000000.0f : 0.0f);
        nib = fmaxf(nib, v);
    }
    float t = softplusf(negq - pos) + softplusf(nib - pos);
    t += __shfl_xor(t, 1, 64);
    t += __shfl_xor(t, 2, 64);
    t += __shfl_xor(t, 4, 64);
    t += __shfl_xor(t, 8, 64);
    t += __shfl_xor(t, 16, 64);
    t += __shfl_xor(t, 32, 64);
    if (b == 0) out[0] = t * (0.5f / 64.0f);
}

extern "C" void kernel_launch(void* const* d_in, const int* in_sizes, int n_in,
                              void* d_out, int out_size, void* d_ws, size_t ws_size,
                              hipStream_t stream) {
    const float* q  = (const float*)d_in[0];   // (64, 32, 128)
    const float* dd = (const float*)d_in[1];   // (64, 256, 128)
    const float* nd = (const float*)d_in[2];   // (64, 256, 128)
    float* out = (float*)d_out;

    float* scores = (float*)d_ws;              // 64*65 fp32

    maxsim_kernel<<<512 + B_SZ, 256, 0, stream>>>(q, dd, nd, scores);

    loss_kernel<<<1, 64, 0, stream>>>(scores, out);
}

// Round 10
// 91.567 us; speedup vs baseline: 1.1916x; 1.1916x over previous
//
#include <hip/hip_runtime.h>
#include <hip/hip_bf16.h>

// Problem constants: B=64, N=32, S=256, D=128
#define B_SZ 64

typedef __attribute__((ext_vector_type(8))) short bf16x8;
typedef __attribute__((ext_vector_type(4))) float f32x4;

static __device__ __forceinline__ unsigned short f2bf(float f) {
    __hip_bfloat16 h = __float2bfloat16(f);
    return *reinterpret_cast<unsigned short*>(&h);
}

// Load 8 consecutive fp32 (32 B), convert to one bf16x8 fragment.
static __device__ __forceinline__ bf16x8 cvt_frag(const float* __restrict__ src) {
    float4 a = reinterpret_cast<const float4*>(src)[0];
    float4 b = reinterpret_cast<const float4*>(src)[1];
    union { bf16x8 v; unsigned short u[8]; } t;
    t.u[0] = f2bf(a.x); t.u[1] = f2bf(a.y); t.u[2] = f2bf(a.z); t.u[3] = f2bf(a.w);
    t.u[4] = f2bf(b.x); t.u[5] = f2bf(b.y); t.u[6] = f2bf(b.z); t.u[7] = f2bf(b.w);
    return t.v;
}

#define MFMA(A, Bv, C) __builtin_amdgcn_mfma_f32_16x16x32_bf16(A, Bv, C, 0, 0, 0)

// Streaming fp32 -> bf16 convert + permute into MFMA fragment order (pays the
// mandatory HBM read once at streaming BW; leaves 8.5 MiB bf16 L3-resident).
// DP (ushort8 idx o): o = doc*4096 + ch*1024 + kk*256 + nt*64 + ln
//    = doc[s = ch*64 + nt*16 + (ln&15)][k = kk*32 + (ln>>4)*8 .. +7]  (doc 64..127 = nd)
// QP (ushort8 idx g): g = b*512 + kk*128 + mt*64 + ln
//    = q[b][n = mt*16 + (ln&15)][k = kk*32 + (ln>>4)*8 .. +7]
__global__ __launch_bounds__(256) void cvt_permute(const float* __restrict__ q,
                                                   const float* __restrict__ dd,
                                                   const float* __restrict__ nd,
                                                   unsigned short* __restrict__ DP,
                                                   unsigned short* __restrict__ QP) {
    const int blk = blockIdx.x, tid = threadIdx.x;
    if (blk < 2048) {
        const int o = blk * 256 + tid;           // 0..524287
        const int doc = o >> 12;
        const int u = o & 4095;
        const int ln = u & 63, nt = (u >> 6) & 3, kk = (u >> 8) & 3, ch = u >> 10;
        const int s  = ch * 64 + nt * 16 + (ln & 15);
        const int k0 = kk * 32 + (ln >> 4) * 8;
        const float* src = ((doc < 64) ? (dd + (size_t)doc * 32768)
                                       : (nd + (size_t)(doc - 64) * 32768)) + s * 128 + k0;
        reinterpret_cast<bf16x8*>(DP)[o] = cvt_frag(src);
    } else {
        const int g = (blk - 2048) * 256 + tid;  // 0..32767
        const int b = g >> 9, u = g & 511;
        const int ln = u & 63, mt = (u >> 6) & 1, kk = u >> 7;
        const int n  = mt * 16 + (ln & 15);
        const int k0 = kk * 32 + (ln >> 4) * 8;
        reinterpret_cast<bf16x8*>(QP)[g] = cvt_frag(q + (size_t)b * 4096 + n * 128 + k0);
    }
}

// MaxSim: 8 queries/WG (2 per wave), FULL 256 s per WG via two 32-KiB s-half
// phases through the same LDS buffer (running per-row max across phases -> exact).
// idx < 512: c = idx>>3, bg = idx&7; wave w: b = bg*8 + 2w + {0,1} -> scores[b*65+c]
// idx >= 512: b = idx-512 vs neg doc b (waves duplicate; wave 0 writes scores[b*65+64])
__global__ __launch_bounds__(256, 3) void maxsim_kernel(const unsigned short* __restrict__ QP,
                                                        const unsigned short* __restrict__ DP,
                                                        float* __restrict__ scores) {
    const int idx = blockIdx.x, tid = threadIdx.x;
    const int wave = tid >> 6, lane = tid & 63;

    __shared__ bf16x8 docB[2048];        // 32 KiB: one s-half in fragment order

    int b0, b1, ccol, dcc;
    const bool isNeg = (idx >= 512);
    if (!isNeg) {
        const int c = idx >> 3, bg = idx & 7;
        b0 = bg * 8 + wave * 2; b1 = b0 + 1;
        ccol = c; dcc = c;
    } else {
        b0 = b1 = idx - 512;
        ccol = B_SZ; dcc = 64 + b0;
    }

    const bf16x8* QP8 = reinterpret_cast<const bf16x8*>(QP);
    const bf16x8* DP8 = reinterpret_cast<const bf16x8*>(DP);

    // ---- one batch: A fragments for this wave's 2 queries ----
    bf16x8 Af[2][4][2];
    {
        const bf16x8* q0 = QP8 + (size_t)b0 * 512 + lane;
        const bf16x8* q1 = QP8 + (size_t)b1 * 512 + lane;
        #pragma unroll
        for (int kk = 0; kk < 4; ++kk) {
            Af[0][kk][0] = q0[kk * 128];
            Af[0][kk][1] = q0[kk * 128 + 64];
            Af[1][kk][0] = q1[kk * 128];
            Af[1][kk][1] = q1[kk * 128 + 64];
        }
    }

    float rmax[2][2][4];                 // [qi][mt][r] running per-row max
    #pragma unroll
    for (int qi = 0; qi < 2; ++qi)
        #pragma unroll
        for (int mt = 0; mt < 2; ++mt)
            #pragma unroll
            for (int r = 0; r < 4; ++r) rmax[qi][mt][r] = -3.0e38f;

    const bf16x8* dbase = DP8 + (size_t)dcc * 4096;

    #pragma unroll
    for (int h = 0; h < 2; ++h) {
        // ---- stage s-half h: contiguous 32 KiB, coalesced, conflict-free ----
        if (h) __syncthreads();          // protect LDS reuse from phase-0 readers
        {
            const bf16x8* src = dbase + h * 2048;
            #pragma unroll
            for (int f = 0; f < 8; ++f)
                docB[f * 256 + tid] = src[f * 256 + tid];
        }
        __syncthreads();

        // ---- compute: 2 sub-chunks x 16 ds_read_b128, each feeding 4 MFMAs ----
        #pragma unroll
        for (int cc = 0; cc < 2; ++cc) {
            f32x4 acc[2][2][4] = {};     // [qi][mt][nt]
            #pragma unroll
            for (int kk = 0; kk < 4; ++kk) {
                #pragma unroll
                for (int nt = 0; nt < 4; ++nt) {
                    bf16x8 Bv = docB[cc * 1024 + kk * 256 + nt * 64 + lane];
                    acc[0][0][nt] = MFMA(Af[0][kk][0], Bv, acc[0][0][nt]);
                    acc[0][1][nt] = MFMA(Af[0][kk][1], Bv, acc[0][1][nt]);
                    acc[1][0][nt] = MFMA(Af[1][kk][0], Bv, acc[1][0][nt]);
                    acc[1][1][nt] = MFMA(Af[1][kk][1], Bv, acc[1][1][nt]);
                }
            }
            #pragma unroll
            for (int qi = 0; qi < 2; ++qi)
                #pragma unroll
                for (int mt = 0; mt < 2; ++mt)
                    #pragma unroll
                    for (int r = 0; r < 4; ++r)
                        rmax[qi][mt][r] = fmaxf(rmax[qi][mt][r],
                            fmaxf(fmaxf(acc[qi][mt][0][r], acc[qi][mt][1][r]),
                                  fmaxf(acc[qi][mt][2][r], acc[qi][mt][3][r])));
        }
    }

    // ---- epilogue: butterfly max over 16 col-residues, sum the 32 rows ----
    #pragma unroll
    for (int qi = 0; qi < 2; ++qi) {
        float part = 0.0f;
        #pragma unroll
        for (int mt = 0; mt < 2; ++mt)
            #pragma unroll
            for (int r = 0; r < 4; ++r) {
                float m = rmax[qi][mt][r];
                m = fmaxf(m, __shfl_xor(m, 1, 64));
                m = fmaxf(m, __shfl_xor(m, 2, 64));
                m = fmaxf(m, __shfl_xor(m, 4, 64));
                m = fmaxf(m, __shfl_xor(m, 8, 64));
                part += m;               // row n = mt*16 + (lane>>4)*4 + r
            }
        part += __shfl_xor(part, 16, 64);
        part += __shfl_xor(part, 32, 64);
        const int b = qi ? b1 : b0;
        if (lane == 0 && (!isNeg || (wave == 0 && qi == 0)))
            scores[(size_t)b * 65 + ccol] = part;
    }
}

static __device__ __forceinline__ float softplusf(float x) {
    return fmaxf(x, 0.0f) + log1pf(expf(-fabsf(x)));
}

__global__ __launch_bounds__(64) void loss_kernel(const float* __restrict__ scores,
                                                  float* __restrict__ out) {
    const int b = threadIdx.x;           // 64 threads = 1 wave
    const float* row = scores + b * 65;
    const float pos  = row[b];
    const float negq = row[64];
    float nib = -1e30f;
    #pragma unroll
    for (int c = 0; c < B_SZ; ++c) {
        float v = row[c] - ((c == b) ? 1000000.0f : 0.0f);
        nib = fmaxf(nib, v);
    }
    float t = softplusf(negq - pos) + softplusf(nib - pos);
    t += __shfl_xor(t, 1, 64);
    t += __shfl_xor(t, 2, 64);
    t += __shfl_xor(t, 4, 64);
    t += __shfl_xor(t, 8, 64);
    t += __shfl_xor(t, 16, 64);
    t += __shfl_xor(t, 32, 64);
    if (b == 0) out[0] = t * (0.5f / 64.0f);
}

extern "C" void kernel_launch(void* const* d_in, const int* in_sizes, int n_in,
                              void* d_out, int out_size, void* d_ws, size_t ws_size,
                              hipStream_t stream) {
    const float* q  = (const float*)d_in[0];   // (64, 32, 128)
    const float* dd = (const float*)d_in[1];   // (64, 256, 128)
    const float* nd = (const float*)d_in[2];   // (64, 256, 128)
    float* out = (float*)d_out;

    // Workspace: DP (128 x 4096 ushort8 = 8 MiB) | QP (512 KiB) | scores (64*65 fp32)
    unsigned short* DP = (unsigned short*)d_ws;
    unsigned short* QP = DP + (size_t)128 * 32768;
    float* scores = (float*)(QP + (size_t)64 * 4096);

    cvt_permute<<<2176, 256, 0, stream>>>(q, dd, nd, DP, QP);

    maxsim_kernel<<<512 + B_SZ, 256, 0, stream>>>(QP, DP, scores);

    loss_kernel<<<1, 64, 0, stream>>>(scores, out);
}